// Round 1
// baseline (1190.581 us; speedup 1.0000x reference)
//
#include <hip/hip_runtime.h>

#define TT 32768   // B*S tokens
#define DD 512
#define HH 2048
#define EE 8
#define HC 1024    // h-chunk: H buffer is [2*TT+128][HC] bf16 per chunk pass

typedef unsigned short u16;
typedef unsigned int u32;
typedef unsigned long long u64;
using short8  = __attribute__((ext_vector_type(8))) short;
using floatx4 = __attribute__((ext_vector_type(4))) float;

__device__ __forceinline__ u16 f2bf(float f) {
  unsigned u = __float_as_uint(f);
  u += 0x7FFFu + ((u >> 16) & 1u);   // RNE; inputs are finite
  return (u16)(u >> 16);
}

// async global->LDS, 16B per lane; lds dest is wave-uniform base + lane*16
__device__ __forceinline__ void gl2lds16(const u16* g, char* l) {
  __builtin_amdgcn_global_load_lds(
      (const __attribute__((address_space(1))) u32*)(const void*)g,
      (__attribute__((address_space(3))) u32*)(void*)l, 16, 0, 0);
}

// ------------- transpose fp32 [E][R][C] -> bf16 [E][C][R] -------------
__global__ void transpose_bf16(const float* __restrict__ in, u16* __restrict__ out, int R, int C) {
  __shared__ float tile[32][33];
  int e = blockIdx.z;
  const float* src = in + (size_t)e * R * C;
  u16* dst = out + (size_t)e * R * C;
  int tx = threadIdx.x, ty = threadIdx.y;
  int c0 = blockIdx.x * 32, r0 = blockIdx.y * 32;
#pragma unroll
  for (int i = 0; i < 32; i += 8)
    tile[ty + i][tx] = src[(size_t)(r0 + ty + i) * C + c0 + tx];
  __syncthreads();
#pragma unroll
  for (int i = 0; i < 32; i += 8)
    dst[(size_t)(c0 + ty + i) * R + r0 + tx] = f2bf(tile[tx][ty + i]);
}

// ------- router pass 1: one wave per token; also emits bf16 x row (fused convert) -------
__global__ void router_topk(const float* __restrict__ x, const float* __restrict__ noise,
                            const float* __restrict__ Wg, const float* __restrict__ bg,
                            const float* __restrict__ Wn, const float* __restrict__ bn,
                            u16* __restrict__ xb, int* __restrict__ topk_i,
                            float* __restrict__ topk_g0, float* __restrict__ topk_g1) {
  const int t = (blockIdx.x * blockDim.x + threadIdx.x) >> 6;
  const int lane = threadIdx.x & 63;
  if (t >= TT) return;
  const float4* xr = (const float4*)(x + (size_t)t * DD) + lane * 2;
  float4 xa = xr[0], xbv = xr[1];
  float xv[8] = {xa.x, xa.y, xa.z, xa.w, xbv.x, xbv.y, xbv.z, xbv.w};
  // fused fp32->bf16 convert of x (wave already holds the whole row)
  {
    ushort4 o0, o1;
    o0.x = f2bf(xa.x); o0.y = f2bf(xa.y); o0.z = f2bf(xa.z); o0.w = f2bf(xa.w);
    o1.x = f2bf(xbv.x); o1.y = f2bf(xbv.y); o1.z = f2bf(xbv.z); o1.w = f2bf(xbv.w);
    ushort4* xo = (ushort4*)(xb + (size_t)t * DD) + lane * 2;
    xo[0] = o0; xo[1] = o1;
  }
  float pg[8], pn[8];
#pragma unroll
  for (int e = 0; e < 8; ++e) { pg[e] = 0.f; pn[e] = 0.f; }
  const float4* wg4 = (const float4*)(Wg + lane * 64);
  const float4* wn4 = (const float4*)(Wn + lane * 64);
#pragma unroll
  for (int j = 0; j < 8; ++j) {
    float xj = xv[j];
    float4 a = wg4[2 * j], b = wg4[2 * j + 1];
    pg[0] += xj * a.x; pg[1] += xj * a.y; pg[2] += xj * a.z; pg[3] += xj * a.w;
    pg[4] += xj * b.x; pg[5] += xj * b.y; pg[6] += xj * b.z; pg[7] += xj * b.w;
    a = wn4[2 * j]; b = wn4[2 * j + 1];
    pn[0] += xj * a.x; pn[1] += xj * a.y; pn[2] += xj * a.z; pn[3] += xj * a.w;
    pn[4] += xj * b.x; pn[5] += xj * b.y; pn[6] += xj * b.z; pn[7] += xj * b.w;
  }
#pragma unroll
  for (int off = 32; off; off >>= 1) {
#pragma unroll
    for (int e = 0; e < 8; ++e) {
      pg[e] += __shfl_xor(pg[e], off);
      pn[e] += __shfl_xor(pn[e], off);
    }
  }
  if (lane == 0) {
    float noisy[8];
#pragma unroll
    for (int e = 0; e < 8; ++e) {
      float nl = pn[e] + bn[e];
      float sp = (nl > 20.f) ? nl : log1pf(expf(nl));
      noisy[e] = pg[e] + bg[e] + noise[(size_t)t * EE + e] * sp;
    }
    int i0 = 0; float v0 = noisy[0];
#pragma unroll
    for (int e = 1; e < 8; ++e) if (noisy[e] > v0) { v0 = noisy[e]; i0 = e; }
    int i1 = -1; float v1 = -3.4e38f;
#pragma unroll
    for (int e = 0; e < 8; ++e) if (e != i0 && noisy[e] > v1) { v1 = noisy[e]; i1 = e; }
    float ed = expf(v1 - v0);
    float inv = 1.f / (1.f + ed);
    topk_i[t] = i0 | (i1 << 8);
    topk_g0[t] = inv;
    topk_g1[t] = ed * inv;
  }
}

// ---------------- router pass 2: bin tokens; 8 global atomics per 256 tokens ----------------
// Also emits token -> (expert, within-expert slot) packed positions for the gather-combine.
__global__ void router_bin(const int* __restrict__ topk_i, const float* __restrict__ tg0,
                           const float* __restrict__ tg1, int* __restrict__ counts,
                           int* __restrict__ lists, float* __restrict__ gates,
                           u32* __restrict__ posA, u32* __restrict__ posB) {
  __shared__ int hist[EE], base_s[EE];
  int t = blockIdx.x * 256 + threadIdx.x;
  if (threadIdx.x < EE) hist[threadIdx.x] = 0;
  __syncthreads();
  int p = topk_i[t];
  int i0 = p & 255, i1 = p >> 8;
  int r0 = atomicAdd(&hist[i0], 1);
  int r1 = atomicAdd(&hist[i1], 1);
  __syncthreads();
  if (threadIdx.x < EE)
    base_s[threadIdx.x] = atomicAdd(&counts[threadIdx.x], hist[threadIdx.x]);
  __syncthreads();
  int s0 = base_s[i0] + r0, s1 = base_s[i1] + r1;
  lists[i0 * TT + s0] = t; gates[i0 * TT + s0] = tg0[t];
  lists[i1 * TT + s1] = t; gates[i1 * TT + s1] = tg1[t];
  posA[t] = (u32)i0 | ((u32)s0 << 8);   // e in low 8 bits, slot (<32768) above
  posB[t] = (u32)i1 | ((u32)s1 << 8);
}

// ============ PASS 1: H_chunk = relu(X_gathered @ W1[:, hoff:hoff+HC] + b1)  (bf16) ============
// m97 structure: 128x128 tile, BK=64, 4 waves x (64x64), XOR-swizzled 16B LDS chunks.
// Persistent: grid x = 8 experts * MS1 seeds; each block walks m-tiles with stride MS1.
// MS sized so grid = 1024 blocks = 4 blocks/CU (VGPR 72 -> 16 waves/CU allowed; LDS 32KB -> 5).
#define MS1 16
#define MS2 32
__global__ __launch_bounds__(256, 4)
void pass1_gemm(const u16* __restrict__ xb, const u16* __restrict__ w1t,
                const float* __restrict__ b1, const int* __restrict__ counts,
                const int* __restrict__ lists, u16* __restrict__ H, int hoff) {
  __shared__ __align__(16) char lds[32768];
  char* ldsA = lds;           // W1^T tile [128 h][64 k]
  char* ldsB = lds + 16384;   // X tile    [128 m][64 k]
  const int e = blockIdx.x & 7;           // expert -> XCD pin for L2 locality
  const int mseed = blockIdx.x >> 3;      // 0..MS1-1
  const int ntile = blockIdx.y;           // 0..HC/128-1
  const int cnt = counts[e];
  int eOff = 0;
#pragma unroll
  for (int j = 0; j < EE; ++j) eOff += (j < e) ? counts[j] : 0;
  const int tid = threadIdx.x, lane = tid & 63, w = tid >> 6;
  const int col16 = lane & 15, quad = lane >> 4;
  const int hh = w & 1, mh = w >> 1;

  int rowi[4], kqi[4];
  const u16* wptr[4];
#pragma unroll
  for (int i = 0; i < 4; ++i) {
    int c = tid + i * 256;
    rowi[i] = c >> 3;
    kqi[i] = (c & 7) ^ (rowi[i] & 7);
    wptr[i] = w1t + (size_t)(e * HH + hoff + ntile * 128 + rowi[i]) * DD + kqi[i] * 8;
  }

  for (int mtile = mseed; mtile * 128 < cnt; mtile += MS1) {
    const u16* xptr[4];
#pragma unroll
    for (int i = 0; i < 4; ++i) {
      int idx = mtile * 128 + rowi[i];
      int tok = (idx < cnt) ? lists[e * TT + idx] : 0;
      xptr[i] = xb + (size_t)tok * DD + kqi[i] * 8;
    }
    floatx4 acc[4][4];
#pragma unroll
    for (int a = 0; a < 4; ++a)
#pragma unroll
      for (int b = 0; b < 4; ++b) acc[a][b] = (floatx4){0.f, 0.f, 0.f, 0.f};

    for (int kc = 0; kc < 8; ++kc) {      // K = 512, BK = 64
      __syncthreads();
#pragma unroll
      for (int i = 0; i < 4; ++i) {
        int off = (tid + i * 256) * 16;
        gl2lds16(wptr[i] + kc * 64, ldsA + off);
        gl2lds16(xptr[i] + kc * 64, ldsB + off);
      }
      __syncthreads();
#pragma unroll
      for (int ks = 0; ks < 2; ++ks) {
        short8 af[4], bf[4];
#pragma unroll
        for (int t4 = 0; t4 < 4; ++t4) {
          int rA = hh * 64 + t4 * 16 + col16;
          af[t4] = *(const short8*)(ldsA + (rA * 8 + ((ks * 4 + quad) ^ (rA & 7))) * 16);
          int rB = mh * 64 + t4 * 16 + col16;
          bf[t4] = *(const short8*)(ldsB + (rB * 8 + ((ks * 4 + quad) ^ (rB & 7))) * 16);
        }
#pragma unroll
        for (int ht = 0; ht < 4; ++ht)
#pragma unroll
          for (int mt = 0; mt < 4; ++mt)
            acc[ht][mt] = __builtin_amdgcn_mfma_f32_16x16x32_bf16(af[ht], bf[mt], acc[ht][mt], 0, 0, 0);
      }
    }
    // epilogue: +b1, relu, bf16 pack (4 consecutive h per lane -> b64 store into H chunk)
#pragma unroll
    for (int ht = 0; ht < 4; ++ht) {
      int hloc = ntile * 128 + hh * 64 + ht * 16 + quad * 4;   // within chunk
      float b1v[4];
#pragma unroll
      for (int r = 0; r < 4; ++r) b1v[r] = b1[e * HH + hoff + hloc + r];
#pragma unroll
      for (int mt = 0; mt < 4; ++mt) {
        int gm = mtile * 128 + mh * 64 + mt * 16 + col16;
        if (gm < cnt) {
          u64 pk = 0;
#pragma unroll
          for (int r = 0; r < 4; ++r) {
            float f = fmaxf(acc[ht][mt][r] + b1v[r], 0.f);
            pk |= (u64)f2bf(f) << (16 * r);
          }
          *(u64*)(H + (size_t)(eOff + gm) * HC + hloc) = pk;
        }
      }
    }
  }
}

// ============ PASS 2: y_slot (+)= H_chunk @ W2[hoff:hoff+HC, :] [+ b2]  ============
// ymode 0: legacy atomicAdd scatter to out (gate applied here)
// ymode 1: plain store  y[slot] = acc + b2     (chunk 0; exactly-once per element)
// ymode 2: plain RMW    y[slot] += acc          (chunk 1)
// Gate + token scatter is deferred to combine_out (no atomics anywhere in modes 1/2).
__global__ __launch_bounds__(256, 4)
void pass2_gemm(const u16* __restrict__ H, const u16* __restrict__ w2t,
                const float* __restrict__ b2, const int* __restrict__ counts,
                const int* __restrict__ lists, const float* __restrict__ gates,
                float* __restrict__ out, int hoff, int addb2,
                float* __restrict__ ybuf, int ymode) {
  __shared__ __align__(16) char lds[32768];
  char* ldsA = lds;           // H tile   [128 m][64 k]
  char* ldsB = lds + 16384;   // W2^T tile[128 d][64 k]
  const int e = blockIdx.x & 7;
  const int mseed = blockIdx.x >> 3;      // 0..MS2-1
  const int ntile = blockIdx.y;           // 0..3 (d block of 128)
  const int cnt = counts[e];
  int eOff = 0;
#pragma unroll
  for (int j = 0; j < EE; ++j) eOff += (j < e) ? counts[j] : 0;
  const int tid = threadIdx.x, lane = tid & 63, w = tid >> 6;
  const int col16 = lane & 15, quad = lane >> 4;
  const int mh = w & 1, dh = w >> 1;

  int rowi[4], kqi[4];
  const u16* wptr[4];
#pragma unroll
  for (int i = 0; i < 4; ++i) {
    int c = tid + i * 256;
    rowi[i] = c >> 3;
    kqi[i] = (c & 7) ^ (rowi[i] & 7);
    wptr[i] = w2t + (size_t)(e * DD + ntile * 128 + rowi[i]) * HH + hoff + kqi[i] * 8;
  }

  for (int mtile = mseed; mtile * 128 < cnt; mtile += MS2) {
    const u16* hptr[4];
#pragma unroll
    for (int i = 0; i < 4; ++i)
      hptr[i] = H + (size_t)(eOff + mtile * 128 + rowi[i]) * HC + kqi[i] * 8;  // pad rows exist

    floatx4 acc[4][4];
#pragma unroll
    for (int a = 0; a < 4; ++a)
#pragma unroll
      for (int b = 0; b < 4; ++b) acc[a][b] = (floatx4){0.f, 0.f, 0.f, 0.f};

    for (int kc = 0; kc < HC / 64; ++kc) {   // K = HC = 1024, BK = 64
      __syncthreads();
#pragma unroll
      for (int i = 0; i < 4; ++i) {
        int off = (tid + i * 256) * 16;
        gl2lds16(hptr[i] + kc * 64, ldsA + off);
        gl2lds16(wptr[i] + kc * 64, ldsB + off);
      }
      __syncthreads();
#pragma unroll
      for (int ks = 0; ks < 2; ++ks) {
        short8 af[4], bf[4];
#pragma unroll
        for (int t4 = 0; t4 < 4; ++t4) {
          int rA = mh * 64 + t4 * 16 + col16;
          af[t4] = *(const short8*)(ldsA + (rA * 8 + ((ks * 4 + quad) ^ (rA & 7))) * 16);
          int rB = dh * 64 + t4 * 16 + col16;
          bf[t4] = *(const short8*)(ldsB + (rB * 8 + ((ks * 4 + quad) ^ (rB & 7))) * 16);
        }
#pragma unroll
        for (int mt = 0; mt < 4; ++mt)
#pragma unroll
          for (int dt = 0; dt < 4; ++dt)
            acc[mt][dt] = __builtin_amdgcn_mfma_f32_16x16x32_bf16(af[mt], bf[dt], acc[mt][dt], 0, 0, 0);
      }
    }
    float b2v[4];
#pragma unroll
    for (int dt = 0; dt < 4; ++dt)
      b2v[dt] = addb2 ? b2[e * DD + ntile * 128 + dh * 64 + dt * 16 + col16] : 0.f;
#pragma unroll
    for (int mt = 0; mt < 4; ++mt) {
#pragma unroll
      for (int r = 0; r < 4; ++r) {
        int idx = mtile * 128 + mh * 64 + mt * 16 + quad * 4 + r;
        if (idx < cnt) {
          if (ymode == 0) {
            int tok = lists[e * TT + idx];
            float g = gates[e * TT + idx];
            float* orow = out + (size_t)tok * DD + ntile * 128 + dh * 64;
#pragma unroll
            for (int dt = 0; dt < 4; ++dt)
              atomicAdd(orow + dt * 16 + col16, g * (acc[mt][dt][r] + b2v[dt]));
          } else {
            float* yrow = ybuf + (size_t)(eOff + idx) * DD + ntile * 128 + dh * 64;
            if (ymode == 1) {
#pragma unroll
              for (int dt = 0; dt < 4; ++dt)
                yrow[dt * 16 + col16] = acc[mt][dt][r] + b2v[dt];
            } else {
#pragma unroll
              for (int dt = 0; dt < 4; ++dt)
                yrow[dt * 16 + col16] += acc[mt][dt][r];
            }
          }
        }
      }
    }
  }
}

// ---- final gather-combine: out[t] = g0 * y[slot0(t)] + g1 * y[slot1(t)]  (no atomics) ----
__global__ __launch_bounds__(256)
void combine_out(const float* __restrict__ y, const int* __restrict__ counts,
                 const u32* __restrict__ posA, const u32* __restrict__ posB,
                 const float* __restrict__ tg0, const float* __restrict__ tg1,
                 float* __restrict__ out) {
  __shared__ int pre[EE];
  if (threadIdx.x < EE) {
    int p = 0;
#pragma unroll
    for (int j = 0; j < EE; ++j) p += (j < (int)threadIdx.x) ? counts[j] : 0;
    pre[threadIdx.x] = p;
  }
  __syncthreads();
  int gid = blockIdx.x * 256 + threadIdx.x;
  int t = gid >> 7;               // D/4 = 128 float4 groups per token row
  int c = (gid & 127) << 2;
  u32 pa = posA[t], pb = posB[t];
  const float4 va = *(const float4*)(y + (size_t)(pre[pa & 255] + (int)(pa >> 8)) * DD + c);
  const float4 vb = *(const float4*)(y + (size_t)(pre[pb & 255] + (int)(pb >> 8)) * DD + c);
  float g0 = tg0[t], g1 = tg1[t];
  float4 o;
  o.x = g0 * va.x + g1 * vb.x;
  o.y = g0 * va.y + g1 * vb.y;
  o.z = g0 * va.z + g1 * vb.z;
  o.w = g0 * va.w + g1 * vb.w;
  *(float4*)(out + (size_t)t * DD + c) = o;
}

extern "C" void kernel_launch(void* const* d_in, const int* in_sizes, int n_in,
                              void* d_out, int out_size, void* d_ws, size_t ws_size,
                              hipStream_t stream) {
  const float* x     = (const float*)d_in[0];
  const float* noise = (const float*)d_in[1];
  const float* Wg    = (const float*)d_in[2];
  const float* bg    = (const float*)d_in[3];
  const float* Wn    = (const float*)d_in[4];
  const float* bn    = (const float*)d_in[5];
  const float* W1    = (const float*)d_in[6];
  const float* b1    = (const float*)d_in[7];
  const float* W2    = (const float*)d_in[8];
  const float* b2    = (const float*)d_in[9];
  float* out = (float*)d_out;
  char* ws = (char*)d_ws;

  // ws layout
  u16*  w1t    = (u16*)(ws + 0x0000000);   // [E][H][D] bf16, 16 MB
  u16*  w2t    = (u16*)(ws + 0x1000000);   // [E][D][H] bf16, 16 MB
  u16*  xb     = (u16*)(ws + 0x2000000);   // [T][D] bf16, 32 MB
  int*  counts = (int*)(ws + 0x4000000);   // [E]
  int*  lists  = (int*)(ws + 0x4001000);   // [E][T] int, 1 MB
  float* gatesp= (float*)(ws + 0x4101000); // [E][T] f32, 1 MB
  int*  topk_i = (int*)(ws + 0x4201000);   // [T]
  float* tg0   = (float*)(ws + 0x4221000); // [T]
  float* tg1   = (float*)(ws + 0x4241000); // [T]
  u32*  posA   = (u32*)(ws + 0x4261000);   // [T] packed (e, slot)
  u32*  posB   = (u32*)(ws + 0x4281000);   // [T]
  u16*  Hbuf   = (u16*)(ws + 0x4300000);   // [2*TT + 128][HC] bf16 = 134.48 MB -> ends 0xC340000
  float* ybuf  = (float*)(ws + 0xC340000); // [2*TT][DD] f32 = 128 MB (optional)
  const size_t need_y = 0xC340000ull + (size_t)2 * TT * DD * 4;  // 338,952,192
  const int useY = (ws_size >= need_y) ? 1 : 0;

  if (!useY) hipMemsetAsync(out, 0, (size_t)TT * DD * 4, stream);  // combine fully overwrites otherwise
  hipMemsetAsync(counts, 0, EE * 4, stream);
  transpose_bf16<<<dim3(HH / 32, DD / 32, EE), dim3(32, 8), 0, stream>>>(W1, w1t, DD, HH);
  transpose_bf16<<<dim3(DD / 32, HH / 32, EE), dim3(32, 8), 0, stream>>>(W2, w2t, HH, DD);
  router_topk<<<TT / 4, 256, 0, stream>>>(x, noise, Wg, bg, Wn, bn, xb, topk_i, tg0, tg1);
  router_bin<<<TT / 256, 256, 0, stream>>>(topk_i, tg0, tg1, counts, lists, gatesp, posA, posB);

  // chunk 0: h in [0, HC)
  pass1_gemm<<<dim3(8 * MS1, HC / 128), 256, 0, stream>>>(xb, w1t, b1, counts, lists, Hbuf, 0);
  pass2_gemm<<<dim3(8 * MS2, 4), 256, 0, stream>>>(Hbuf, w2t, b2, counts, lists, gatesp, out, 0, 1,
                                                   ybuf, useY ? 1 : 0);
  // chunk 1: h in [HC, 2*HC)
  pass1_gemm<<<dim3(8 * MS1, HC / 128), 256, 0, stream>>>(xb, w1t, b1, counts, lists, Hbuf, HC);
  pass2_gemm<<<dim3(8 * MS2, 4), 256, 0, stream>>>(Hbuf, w2t, b2, counts, lists, gatesp, out, HC, 0,
                                                   ybuf, useY ? 2 : 0);
  if (useY)
    combine_out<<<(TT * DD / 4) / 256, 256, 0, stream>>>(ybuf, counts, posA, posB, tg0, tg1, out);
}